// Round 7
// baseline (367.217 us; speedup 1.0000x reference)
//
#include <hip/hip_runtime.h>
#include <hip/hip_bf16.h>
#include <cstddef>

// Problem constants (from reference)
#define QN 10000
#define DD 64
#define MM 50
#define BB 64
#define TT 512
#define WPAD 52     // w_buf row stride in floats
#define CC 16       // chunks
#define LL 32       // steps per chunk = TT/CC
#define NROW 32704  // BB*(TT-1)

__device__ __forceinline__ float sigf(float x) {
  return 1.f / (1.f + __expf(-x));
}
__device__ __forceinline__ float tanhf_fast(float x) {
  const float t2 = __expf(2.f * x);
  return 1.f - 2.f / (t2 + 1.f);
}

// ---------------------------------------------------------------------------
// k0: MkT64[i][m] = Mk[m][i], zero-padded to 64 cols (m>=50 -> 0).
// ---------------------------------------------------------------------------
__global__ __launch_bounds__(64) void k0_mkT(
    const float* __restrict__ Mk, float* __restrict__ MkT64) {
  for (int idx = (int)threadIdx.x; idx < 4096; idx += 64) {
    const int i = idx >> 6, m = idx & 63;
    MkT64[idx] = (m < MM) ? Mk[m * 64 + i] : 0.f;
  }
}

// ---------------------------------------------------------------------------
// k1: lane = row, x in VGPRs (loaded once), weights streamed via uniform
// s_load in 16-float d-tiles (prefetchable within SGPR budget).
//   blocks [0,512):    w = softmax(k @ Mk^T)   (MkT64, 64 padded cols)
//   blocks [512,1024): e = sigmoid(v@e_W+e_b); a = tanh(v@a_W+a_b)
// ---------------------------------------------------------------------------
__global__ __launch_bounds__(64, 2) void k1_gemv(
    const int* __restrict__ question, const int* __restrict__ response,
    const float* __restrict__ k_emb, const float* __restrict__ v_emb,
    const float* __restrict__ MkT64,
    const float* __restrict__ e_W, const float* __restrict__ e_b,
    const float* __restrict__ a_W, const float* __restrict__ a_b,
    float* __restrict__ w_buf, float* __restrict__ e_buf, float* __restrict__ a_buf) {
  const int lane = (int)threadIdx.x;
  const int blk = (int)blockIdx.x;

  if (blk < 512) {
    const int row = blk * 64 + lane;
    const int q = question[row];
    const float* __restrict__ krow = k_emb + (size_t)q * 64;
    float x[64];
#pragma unroll
    for (int i = 0; i < 64; i += 4) {
      const float4 t = *(const float4*)(krow + i);
      x[i] = t.x; x[i + 1] = t.y; x[i + 2] = t.z; x[i + 3] = t.w;
    }
    float l[64];
#pragma unroll
    for (int m = 0; m < 64; ++m) l[m] = 0.f;
#pragma unroll
    for (int dt = 0; dt < 4; ++dt) {
#pragma unroll
      for (int i = 0; i < 64; ++i) {
        const float* __restrict__ wr = MkT64 + i * 64 + dt * 16;  // uniform
#pragma unroll
        for (int d = 0; d < 16; ++d)
          l[dt * 16 + d] = fmaf(x[i], wr[d], l[dt * 16 + d]);
      }
    }
    // per-lane softmax over l[0..49]
    float mx = l[0];
#pragma unroll
    for (int m = 1; m < 50; ++m) mx = fmaxf(mx, l[m]);
    float s = 0.f;
#pragma unroll
    for (int m = 0; m < 50; ++m) { l[m] = __expf(l[m] - mx); s += l[m]; }
    const float inv = 1.f / s;
#pragma unroll
    for (int m = 0; m < 50; ++m) l[m] *= inv;
    l[50] = 0.f; l[51] = 0.f;
    float* __restrict__ wo = w_buf + (size_t)row * WPAD;
#pragma unroll
    for (int m = 0; m < 52; m += 4) {
      float4 o; o.x = l[m]; o.y = l[m + 1]; o.z = l[m + 2]; o.w = l[m + 3];
      *(float4*)(wo + m) = o;
    }
  } else {
    const int row = (blk - 512) * 64 + lane;
    const int q = question[row];
    const int r = response[row];
    const float* __restrict__ vrow = v_emb + ((size_t)q + (size_t)QN * r) * 64;
    float x[64];
#pragma unroll
    for (int i = 0; i < 64; i += 4) {
      const float4 t = *(const float4*)(vrow + i);
      x[i] = t.x; x[i + 1] = t.y; x[i + 2] = t.z; x[i + 3] = t.w;
    }
    float* __restrict__ oe = e_buf + (size_t)row * 64;
    float* __restrict__ oa = a_buf + (size_t)row * 64;
    // e pass then a pass, 16-wide d-tiles
#pragma unroll
    for (int dt = 0; dt < 4; ++dt) {
      float acc[16];
#pragma unroll
      for (int d = 0; d < 16; ++d) acc[d] = 0.f;
#pragma unroll
      for (int i = 0; i < 64; ++i) {
        const float* __restrict__ wr = e_W + i * 64 + dt * 16;    // uniform
#pragma unroll
        for (int d = 0; d < 16; ++d) acc[d] = fmaf(x[i], wr[d], acc[d]);
      }
#pragma unroll
      for (int d = 0; d < 16; d += 4) {
        float4 ov;
        ov.x = sigf(acc[d]     + e_b[dt * 16 + d]);
        ov.y = sigf(acc[d + 1] + e_b[dt * 16 + d + 1]);
        ov.z = sigf(acc[d + 2] + e_b[dt * 16 + d + 2]);
        ov.w = sigf(acc[d + 3] + e_b[dt * 16 + d + 3]);
        *(float4*)(oe + dt * 16 + d) = ov;
      }
    }
#pragma unroll
    for (int dt = 0; dt < 4; ++dt) {
      float acc[16];
#pragma unroll
      for (int d = 0; d < 16; ++d) acc[d] = 0.f;
#pragma unroll
      for (int i = 0; i < 64; ++i) {
        const float* __restrict__ wr = a_W + i * 64 + dt * 16;    // uniform
#pragma unroll
        for (int d = 0; d < 16; ++d) acc[d] = fmaf(x[i], wr[d], acc[d]);
      }
#pragma unroll
      for (int d = 0; d < 16; d += 4) {
        float4 ov;
        ov.x = tanhf_fast(acc[d]     + a_b[dt * 16 + d]);
        ov.y = tanhf_fast(acc[d + 1] + a_b[dt * 16 + d + 1]);
        ov.z = tanhf_fast(acc[d + 2] + a_b[dt * 16 + d + 2]);
        ov.w = tanhf_fast(acc[d + 3] + a_b[dt * 16 + d + 3]);
        *(float4*)(oa + dt * 16 + d) = ov;
      }
    }
  }
}

// ---------------------------------------------------------------------------
// kA: composed affine (A,B) per (m,d) per (b,chunk). One wave per unit;
// lane = d. w-row: coalesced lane load -> LDS double-buffer -> b128
// broadcast reads (free). Prefetch next row one step ahead.
// ---------------------------------------------------------------------------
__global__ __launch_bounds__(64, 2) void kA_chunk(
    const float* __restrict__ w_buf, const float* __restrict__ e_buf,
    const float* __restrict__ a_buf, const float* __restrict__ mask,
    float* __restrict__ A_arr, float* __restrict__ B_arr) {
  __shared__ float wst[2][64];
  const int lane = (int)threadIdx.x;
  const int unit = (int)blockIdx.x;                    // b*CC + c
  const int b = unit >> 4;
  const int c = unit & (CC - 1);
  const int lcl = lane < WPAD ? lane : (WPAD - 1);

  float Am[MM], Bm[MM];
#pragma unroll
  for (int m = 0; m < MM; ++m) { Am[m] = 1.f; Bm[m] = 0.f; }

  const size_t row0 = (size_t)b * TT + c * LL;
  wst[0][lane] = w_buf[row0 * WPAD + lcl];
#pragma unroll
  for (int j = 0; j < LL; ++j) {
    const size_t row = row0 + j;
    float wnext = 0.f;
    if (j + 1 < LL) wnext = w_buf[(row + 1) * WPAD + lcl];  // prefetch
    const float ed = e_buf[row * 64 + lane];
    const float ad = a_buf[row * 64 + lane];
    const float mv = mask[row];                        // uniform
    float w[52];
#pragma unroll
    for (int m4 = 0; m4 < 52; m4 += 4) {
      const float4 t = *(const float4*)(&wst[j & 1][m4]);   // broadcast
      w[m4] = t.x; w[m4 + 1] = t.y; w[m4 + 2] = t.z; w[m4 + 3] = t.w;
    }
    if (mv == 1.0f) {
#pragma unroll
      for (int m = 0; m < MM; ++m) {
        const float al = fmaf(-w[m], ed, 1.0f);
        Am[m] *= al;
        Bm[m] = fmaf(Bm[m], al, w[m] * ad);
      }
    }
    wst[(j + 1) & 1][lane] = wnext;
  }
  float* __restrict__ Ad = A_arr + (size_t)unit * (MM * 64);
  float* __restrict__ Bd = B_arr + (size_t)unit * (MM * 64);
#pragma unroll
  for (int m = 0; m < MM; ++m) {
    Ad[m * 64 + lane] = Am[m];
    Bd[m * 64 + lane] = Bm[m];
  }
}

// ---------------------------------------------------------------------------
// kB: chunk-entry states. Parallel over B*M*D = 204,800 elements; CC=16
// chain fully unrolled, all loads issued up front.
// ---------------------------------------------------------------------------
__global__ __launch_bounds__(256) void kB_entry(
    const float* __restrict__ A_arr, const float* __restrict__ B_arr,
    const float* __restrict__ Mv0, float* __restrict__ entry) {
  const int idx = blockIdx.x * 256 + (int)threadIdx.x; // < 204800
  const int b = idx / (MM * 64);
  const int r = idx - b * (MM * 64);
  const size_t base = (size_t)b * CC * (MM * 64) + r;

  float Ac[CC], Bc[CC];
#pragma unroll
  for (int c = 0; c < CC; ++c) {
    Ac[c] = A_arr[base + (size_t)c * (MM * 64)];
    Bc[c] = B_arr[base + (size_t)c * (MM * 64)];
  }
  float s = Mv0[r];
#pragma unroll
  for (int c = 0; c < CC; ++c) {
    entry[base + (size_t)c * (MM * 64)] = s;
    s = fmaf(Ac[c], s, Bc[c]);
  }
}

// ---------------------------------------------------------------------------
// kC: replay each chunk from its entry state, emitting reads TRANSPOSED:
// read_T[d][out_row] so k3's loads are coalesced. Same LDS w-row scheme as kA.
// ---------------------------------------------------------------------------
__global__ __launch_bounds__(64, 2) void kC_read(
    const float* __restrict__ w_buf, const float* __restrict__ e_buf,
    const float* __restrict__ a_buf, const float* __restrict__ mask,
    const float* __restrict__ entry, float* __restrict__ read_T) {
  __shared__ float wst[2][64];
  const int lane = (int)threadIdx.x;                   // = d
  const int unit = (int)blockIdx.x;                    // b*CC + c
  const int b = unit >> 4;
  const int c = unit & (CC - 1);
  const int lcl = lane < WPAD ? lane : (WPAD - 1);

  float s[MM];
  const float* __restrict__ ep = entry + (size_t)unit * (MM * 64);
#pragma unroll
  for (int m = 0; m < MM; ++m) s[m] = ep[m * 64 + lane];

  const size_t row0 = (size_t)b * TT + c * LL;
  wst[0][lane] = w_buf[row0 * WPAD + lcl];
#pragma unroll
  for (int j = 0; j < LL; ++j) {
    const int t = c * LL + j;
    const size_t row = row0 + j;
    float wnext = 0.f;
    if (j + 1 < LL) wnext = w_buf[(row + 1) * WPAD + lcl];  // prefetch
    const float ed = e_buf[row * 64 + lane];
    const float ad = a_buf[row * 64 + lane];
    const float mv = mask[row];                        // uniform
    float w[52];
#pragma unroll
    for (int m4 = 0; m4 < 52; m4 += 4) {
      const float4 tt = *(const float4*)(&wst[j & 1][m4]);  // broadcast
      w[m4] = tt.x; w[m4 + 1] = tt.y; w[m4 + 2] = tt.z; w[m4 + 3] = tt.w;
    }
    if (t >= 1) {                                      // uniform branch
      float a0 = 0.f, a1 = 0.f;
#pragma unroll
      for (int m = 0; m < MM; m += 2) {
        a0 = fmaf(w[m], s[m], a0);
        a1 = fmaf(w[m + 1], s[m + 1], a1);
      }
      // transposed scatter store (fire-and-forget)
      read_T[(size_t)lane * NROW + (size_t)b * (TT - 1) + (t - 1)] = a0 + a1;
    }
    if (mv == 1.0f) {
#pragma unroll
      for (int m = 0; m < MM; ++m)
        s[m] = fmaf(w[m], fmaf(-s[m], ed, ad), s[m]);
    }
    wst[(j + 1) & 1][lane] = wnext;
  }
}

// ---------------------------------------------------------------------------
// k3: lane = row; x[128] fully in VGPRs (read part coalesced from read_T,
// k part gathered once); f_W streamed via uniform s_load in 16-float d-tiles.
// ---------------------------------------------------------------------------
__global__ __launch_bounds__(64, 2) void k3_out(
    const int* __restrict__ question, const float* __restrict__ k_emb,
    const float* __restrict__ read_T,
    const float* __restrict__ f_W, const float* __restrict__ f_b,
    const float* __restrict__ p_W, const float* __restrict__ p_b,
    float* __restrict__ out) {
  const int lane = (int)threadIdx.x;
  const int row = (int)blockIdx.x * 64 + lane;         // 0..32703
  const int b = row / (TT - 1);
  const int tp = row - b * (TT - 1);
  const int qn = question[b * TT + tp + 1];
  const float* __restrict__ krow = k_emb + (size_t)qn * 64;

  float x[128];
#pragma unroll
  for (int i = 0; i < 64; ++i)
    x[i] = read_T[(size_t)i * NROW + row];             // coalesced dword
#pragma unroll
  for (int i = 0; i < 64; i += 4) {
    const float4 t = *(const float4*)(krow + i);       // per-lane gather
    x[64 + i] = t.x; x[64 + i + 1] = t.y;
    x[64 + i + 2] = t.z; x[64 + i + 3] = t.w;
  }

  float p = 0.f;
#pragma unroll
  for (int dt = 0; dt < 4; ++dt) {
    float f[16];
#pragma unroll
    for (int d = 0; d < 16; ++d) f[d] = 0.f;
#pragma unroll
    for (int i = 0; i < 128; ++i) {
      const float* __restrict__ wr = f_W + i * 64 + dt * 16;      // uniform
#pragma unroll
      for (int d = 0; d < 16; ++d) f[d] = fmaf(x[i], wr[d], f[d]);
    }
#pragma unroll
    for (int d = 0; d < 16; ++d) {
      const float fv = tanhf_fast(f[d] + f_b[dt * 16 + d]);
      p = fmaf(fv, p_W[dt * 16 + d], p);
    }
  }
  out[row] = p + p_b[0];
}

// ---------------------------------------------------------------------------
extern "C" void kernel_launch(void* const* d_in, const int* in_sizes, int n_in,
                              void* d_out, int out_size, void* d_ws, size_t ws_size,
                              hipStream_t stream) {
  const int*   question = (const int*)d_in[0];
  const int*   response = (const int*)d_in[1];
  const float* mask     = (const float*)d_in[2];
  const float* k_emb    = (const float*)d_in[3];
  const float* v_emb    = (const float*)d_in[4];
  const float* Mk       = (const float*)d_in[5];
  const float* Mv0      = (const float*)d_in[6];
  const float* e_W      = (const float*)d_in[7];
  const float* e_b      = (const float*)d_in[8];
  const float* a_W      = (const float*)d_in[9];
  const float* a_b      = (const float*)d_in[10];
  const float* f_W      = (const float*)d_in[11];
  const float* f_b      = (const float*)d_in[12];
  const float* p_W      = (const float*)d_in[13];
  const float* p_b      = (const float*)d_in[14];
  float* out = (float*)d_out;

  // workspace layout (floats)
  const size_t wN  = (size_t)BB * TT * WPAD;       // 1,703,936
  const size_t eN  = (size_t)BB * TT * 64;         // 2,097,152
  const size_t rN  = (size_t)64 * NROW;            // 2,093,056
  const size_t abN = (size_t)BB * CC * MM * 64;    // 3,276,800
  float* ws = (float*)d_ws;
  float* MkT64    = ws;                            // 4096
  float* w_buf    = MkT64 + 4096;
  float* e_buf    = w_buf + wN;
  float* a_buf    = e_buf + eN;
  float* read_T   = a_buf + eN;
  float* A_arr    = read_T + rN;
  float* B_arr    = A_arr + abN;
  float* entry    = B_arr + abN;
  // total ~ 17.8M floats = 71 MB (< ws_size)

  hipLaunchKernelGGL(k0_mkT, dim3(1), dim3(64), 0, stream, Mk, MkT64);
  hipLaunchKernelGGL(k1_gemv, dim3(1024), dim3(64), 0, stream,
                     question, response, k_emb, v_emb, MkT64, e_W, e_b, a_W, a_b,
                     w_buf, e_buf, a_buf);
  hipLaunchKernelGGL(kA_chunk, dim3(BB * CC), dim3(64), 0, stream,
                     w_buf, e_buf, a_buf, mask, A_arr, B_arr);
  hipLaunchKernelGGL(kB_entry, dim3((BB * MM * 64) / 256), dim3(256), 0, stream,
                     A_arr, B_arr, Mv0, entry);
  hipLaunchKernelGGL(kC_read, dim3(BB * CC), dim3(64), 0, stream,
                     w_buf, e_buf, a_buf, mask, entry, read_T);
  hipLaunchKernelGGL(k3_out, dim3(511), dim3(64), 0, stream,
                     question, k_emb, read_T, f_W, f_b, p_W, p_b, out);
}